// Round 3
// baseline (181.896 us; speedup 1.0000x reference)
//
#include <hip/hip_runtime.h>

#define NS   16
#define NV   4
#define FEAT 48          // N_EDGE_FEAT
#define WN   320         // W_NUMEL
#define MSG  28          // logical message width
#define MSGP 32          // padded msg row stride (floats) -> 128 B rows

typedef __bf16 bf16x8 __attribute__((ext_vector_type(8)));
typedef float  f32x4  __attribute__((ext_vector_type(4)));

#define PK1_ELEMS (2 * 3 * 64 * 8)    // 3072 bf16
#define PK2_ELEMS (2 * 20 * 64 * 8)   // 20480 bf16

// ---------------- weight packing into MFMA B-fragment layout ----------------
// frag (ks, nt): lane l holds B[k = ks*32 + 8*(l>>4) + j][n = nt*16 + (l&15)], j=0..7
__global__ void pack_weights(const float* __restrict__ fc1_w,
                             const float* __restrict__ fc2_w,
                             __bf16* __restrict__ pk1,
                             __bf16* __restrict__ pk2)
{
    const int idx = blockIdx.x * blockDim.x + threadIdx.x;
    const int stride = gridDim.x * blockDim.x;
    for (int i = idx; i < PK1_ELEMS; i += stride) {
        const int j = i & 7, lane = (i >> 3) & 63, t = i >> 9;  // t = ks*3 + nt
        const int nt = t % 3, ks = t / 3;
        const int k = ks * 32 + 8 * (lane >> 4) + j;
        const int n = nt * 16 + (lane & 15);
        pk1[i] = (k < FEAT) ? (__bf16)fc1_w[k * FEAT + n] : (__bf16)0.f;
    }
    for (int i = idx; i < PK2_ELEMS; i += stride) {
        const int j = i & 7, lane = (i >> 3) & 63, t = i >> 9;  // t = ks*20 + nt
        const int nt = t % 20, ks = t / 20;
        const int k = ks * 32 + 8 * (lane >> 4) + j;
        const int n = nt * 16 + (lane & 15);
        pk2[i] = (k < FEAT) ? (__bf16)fc2_w[k * WN + n] : (__bf16)0.f;
    }
}

// ---------------- CSR build ----------------
__global__ void histo_kernel(const int* __restrict__ src, int* __restrict__ count, int E)
{
    const int e = blockIdx.x * blockDim.x + threadIdx.x;
    if (e < E) atomicAdd(&count[src[e]], 1);
}

// exclusive scan within 256-blocks; bsum[b] = block total
__global__ void scan_block(const int* __restrict__ in, int* __restrict__ outExcl,
                           int* __restrict__ bsum, int n)
{
    __shared__ int s[256];
    const int tid = threadIdx.x;
    const int i = blockIdx.x * 256 + tid;
    int v = (i < n) ? in[i] : 0;
    int acc = v;
    s[tid] = acc;
    __syncthreads();
    #pragma unroll
    for (int off = 1; off < 256; off <<= 1) {
        int t = (tid >= off) ? s[tid - off] : 0;
        __syncthreads();
        acc += t;
        s[tid] = acc;
        __syncthreads();
    }
    if (i < n) outExcl[i] = acc - v;
    if (tid == 255) bsum[blockIdx.x] = acc;
}

__global__ void fill_csr(const int* __restrict__ src,
                         const int* __restrict__ base, const int* __restrict__ boff,
                         int* __restrict__ cursor, int* __restrict__ elist, int E)
{
    const int e = blockIdx.x * blockDim.x + threadIdx.x;
    if (e < E) {
        const int s = src[e];
        const int pos = atomicAdd(&cursor[s], 1);
        elist[base[s] + boff[s >> 8] + pos] = e;
    }
}

// ---------------- fused edge compute (fc1 -> relu -> fc2 -> tensor product) ----------------
// MODE 0: write msg[e][0..27] (padded stride MSGP), no atomics.
// MODE 1: legacy atomic scatter into out_acc[N][28] + cnt[N].
template<int MODE>
__global__ __launch_bounds__(256, 4) void edge_mfma_kernel(
    const float* __restrict__ node_attr,
    const float* __restrict__ edge_attr,
    const float* __restrict__ edge_sh,
    const float* __restrict__ fc1_b,
    const float* __restrict__ fc2_b,
    const int*   __restrict__ edge_index,
    const __bf16* __restrict__ pk1,
    const __bf16* __restrict__ pk2,
    float* __restrict__ dst0,    // MODE0: msg[E][MSGP]; MODE1: out_acc[N][28]
    float* __restrict__ cnt,     // MODE1 only
    int E)
{
    // all LDS is wave-private: no __syncthreads needed
    __shared__ __bf16 sH[4][32][56];    // h tile (row stride 112 B)
    __shared__ float  sX[4][32][17];    // x = node_attr[dst]
    __shared__ float  sSh[4][32][4];    // sh0..sh3 per edge
    __shared__ int    sSrc[4][32];      // MODE1 only

    const int tid = threadIdx.x;
    const int w   = tid >> 6;
    const int l   = tid & 63;
    const int q   = l >> 4;
    const int r16 = l & 15;
    const int e0  = (blockIdx.x * 4 + w) * 32;   // this wave's 32 edges (2 MFMA tiles)

    const float4 z4 = make_float4(0.f, 0.f, 0.f, 0.f);

    // ---- gather A fragments (ea, K padded 48->64) for both tiles ----
    bf16x8 a0[2], a1[2];
    #pragma unroll
    for (int t = 0; t < 2; ++t) {
        const int e  = e0 + 16 * t + r16;
        const bool ev = (e < E);
        float4 fa = z4, fb = z4;
        if (ev) {
            const float* p0 = (q < 2)
                ? (edge_attr + (size_t)e * NS + q * 8)
                : (node_attr + (size_t)edge_index[e] * NS + (q - 2) * 8);
            fa = reinterpret_cast<const float4*>(p0)[0];
            fb = reinterpret_cast<const float4*>(p0)[1];
        }
        a0[t][0]=(__bf16)fa.x; a0[t][1]=(__bf16)fa.y; a0[t][2]=(__bf16)fa.z; a0[t][3]=(__bf16)fa.w;
        a0[t][4]=(__bf16)fb.x; a0[t][5]=(__bf16)fb.y; a0[t][6]=(__bf16)fb.z; a0[t][7]=(__bf16)fb.w;

        if (q < 2) {
            float4 ga = z4, gb = z4;
            if (ev) {
                const float* p1 = node_attr + (size_t)edge_index[E + e] * NS + q * 8;
                ga = reinterpret_cast<const float4*>(p1)[0];
                gb = reinterpret_cast<const float4*>(p1)[1];
            }
            a1[t][0]=(__bf16)ga.x; a1[t][1]=(__bf16)ga.y; a1[t][2]=(__bf16)ga.z; a1[t][3]=(__bf16)ga.w;
            a1[t][4]=(__bf16)gb.x; a1[t][5]=(__bf16)gb.y; a1[t][6]=(__bf16)gb.z; a1[t][7]=(__bf16)gb.w;
            float* xp = &sX[w][16 * t + r16][q * 8];
            xp[0]=ga.x; xp[1]=ga.y; xp[2]=ga.z; xp[3]=ga.w;
            xp[4]=gb.x; xp[5]=gb.y; xp[6]=gb.z; xp[7]=gb.w;
        } else {
            #pragma unroll
            for (int j = 0; j < 8; ++j) a1[t][j] = (__bf16)0.f;
        }
    }
    if (l < 32) {
        const int e = e0 + l;
        const bool ev = (e < E);
        if (MODE == 1) sSrc[w][l] = ev ? edge_index[e] : 0;
        #pragma unroll
        for (int mm = 0; mm < 4; ++mm)
            sSh[w][l][mm] = ev ? edge_sh[(size_t)e * 9 + mm] : 0.f;
    }

    // ---- fc1: relu(ea @ fc1_w + b) -> sH (bf16), B-frags shared across tiles ----
    #pragma unroll
    for (int nt = 0; nt < 3; ++nt) {
        bf16x8 b0 = *reinterpret_cast<const bf16x8*>(pk1 + ((size_t)(0 * 3 + nt) * 64 + l) * 8);
        bf16x8 b1 = *reinterpret_cast<const bf16x8*>(pk1 + ((size_t)(1 * 3 + nt) * 64 + l) * 8);
        const float bias = fc1_b[nt * 16 + r16];
        #pragma unroll
        for (int t = 0; t < 2; ++t) {
            f32x4 acc = {bias, bias, bias, bias};
            acc = __builtin_amdgcn_mfma_f32_16x16x32_bf16(a0[t], b0, acc, 0, 0, 0);
            acc = __builtin_amdgcn_mfma_f32_16x16x32_bf16(a1[t], b1, acc, 0, 0, 0);
            #pragma unroll
            for (int g = 0; g < 4; ++g)
                sH[w][16 * t + 4 * q + g][nt * 16 + r16] = (__bf16)fmaxf(acc[g], 0.f);
        }
    }

    // ---- h -> A fragments ----
    bf16x8 ha0[2], ha1[2];
    #pragma unroll
    for (int t = 0; t < 2; ++t) {
        ha0[t] = *reinterpret_cast<const bf16x8*>(&sH[w][16 * t + r16][q * 8]);
        if (q < 2) {
            ha1[t] = *reinterpret_cast<const bf16x8*>(&sH[w][16 * t + r16][32 + q * 8]);
        } else {
            #pragma unroll
            for (int j = 0; j < 8; ++j) ha1[t][j] = (__bf16)0.f;
        }
    }

    // ---- fc2 + fused tensor product ----
    f32x4 acc0[2] = {{0.f,0.f,0.f,0.f},{0.f,0.f,0.f,0.f}};
    f32x4 acc1[2] = {{0.f,0.f,0.f,0.f},{0.f,0.f,0.f,0.f}};
    const int row = 4 * q;
    #pragma unroll 4
    for (int nt = 0; nt < 20; ++nt) {
        bf16x8 b0 = *reinterpret_cast<const bf16x8*>(pk2 + ((size_t)(0 * 20 + nt) * 64 + l) * 8);
        bf16x8 b1 = *reinterpret_cast<const bf16x8*>(pk2 + ((size_t)(1 * 20 + nt) * 64 + l) * 8);
        const float bias = fc2_b[nt * 16 + r16];
        #pragma unroll
        for (int t = 0; t < 2; ++t) {
            f32x4 d = {bias, bias, bias, bias};
            d = __builtin_amdgcn_mfma_f32_16x16x32_bf16(ha0[t], b0, d, 0, 0, 0);
            d = __builtin_amdgcn_mfma_f32_16x16x32_bf16(ha1[t], b1, d, 0, 0, 0);
            if (nt < 16) {
                #pragma unroll
                for (int g = 0; g < 4; ++g)
                    acc0[t][g] = fmaf(sX[w][16 * t + row + g][nt], d[g], acc0[t][g]);
            } else {
                const int u = (nt - 16) * 4 + (r16 >> 2);
                #pragma unroll
                for (int g = 0; g < 4; ++g)
                    acc1[t][g] = fmaf(sX[w][16 * t + row + g][u], d[g], acc1[t][g]);
            }
        }
    }

    const float inv = 0.25f;   // 1/sqrt(16)

    // ---- out1 reduction across lane groups (bits 2,3) ----
    #pragma unroll
    for (int t = 0; t < 2; ++t)
        #pragma unroll
        for (int g = 0; g < 4; ++g) {
            float s = acc1[t][g];
            s += __shfl_xor(s, 4);
            s += __shfl_xor(s, 8);
            acc1[t][g] = s;
        }
    const int mcomp = r16 >> 2;       // 0..3 (3 idle)
    const int vidx  = l & 3;

    if (MODE == 0) {
        float* __restrict__ msg = dst0;
        #pragma unroll
        for (int t = 0; t < 2; ++t)
            #pragma unroll
            for (int g = 0; g < 4; ++g) {
                const int rr = 16 * t + row + g;
                const int e  = e0 + rr;
                if (e < E)
                    msg[(size_t)e * MSGP + r16] = inv * sSh[w][rr][0] * acc0[t][g];
            }
        if (mcomp < 3) {
            #pragma unroll
            for (int t = 0; t < 2; ++t)
                #pragma unroll
                for (int g = 0; g < 4; ++g) {
                    const int rr = 16 * t + row + g;
                    const int e  = e0 + rr;
                    if (e < E)
                        msg[(size_t)e * MSGP + NS + vidx * 3 + mcomp] =
                            inv * acc1[t][g] * sSh[w][rr][1 + mcomp];
                }
        }
    } else {
        float* __restrict__ out_acc = dst0;
        #pragma unroll
        for (int t = 0; t < 2; ++t)
            #pragma unroll
            for (int g = 0; g < 4; ++g) {
                const int rr = 16 * t + row + g;
                if (e0 + rr < E)
                    atomicAdd(&out_acc[(size_t)sSrc[w][rr] * MSG + r16],
                              inv * sSh[w][rr][0] * acc0[t][g]);
            }
        if (mcomp < 3) {
            #pragma unroll
            for (int t = 0; t < 2; ++t)
                #pragma unroll
                for (int g = 0; g < 4; ++g) {
                    const int rr = 16 * t + row + g;
                    if (e0 + rr < E)
                        atomicAdd(&out_acc[(size_t)sSrc[w][rr] * MSG + NS + vidx * 3 + mcomp],
                                  inv * acc1[t][g] * sSh[w][rr][1 + mcomp]);
                }
        }
        if (r16 == 0) {
            #pragma unroll
            for (int t = 0; t < 2; ++t)
                #pragma unroll
                for (int g = 0; g < 4; ++g) {
                    const int rr = 16 * t + row + g;
                    if (e0 + rr < E) atomicAdd(&cnt[sSrc[w][rr]], 1.f);
                }
        }
    }
}

// ---------------- node gather-reduce: mean over own edges, no atomics ----------------
__global__ __launch_bounds__(256) void node_reduce(
    const float* __restrict__ msg,
    const int* __restrict__ elist,
    const int* __restrict__ count,
    const int* __restrict__ base,
    const int* __restrict__ boff,
    float* __restrict__ out, int N)
{
    const int tid  = threadIdx.x;
    const int w    = tid >> 6;
    const int l    = tid & 63;
    const int slot = l >> 5;
    const int c    = l & 31;
    const int n    = blockIdx.x * 8 + w * 2 + slot;
    if (n >= N) return;

    const int deg = count[n];
    const int b   = base[n] + boff[n >> 8];
    float acc = 0.f;
    int j = 0;
    for (; j + 1 < deg; j += 2) {
        const int e1 = elist[b + j];
        const int e2 = elist[b + j + 1];
        float v1 = 0.f, v2 = 0.f;
        if (c < MSG) {
            v1 = msg[(size_t)e1 * MSGP + c];
            v2 = msg[(size_t)e2 * MSGP + c];
        }
        acc += v1 + v2;
    }
    if (j < deg && c < MSG) acc += msg[(size_t)elist[b + j] * MSGP + c];
    if (c < MSG) out[(size_t)n * MSG + c] = acc / fmaxf((float)deg, 1.f);
}

__global__ void finalize_kernel(float* __restrict__ out,
                                const float* __restrict__ cnt, int total)
{
    const int idx = blockIdx.x * blockDim.x + threadIdx.x;
    if (idx < total) {
        const int n = idx / MSG;
        out[idx] = out[idx] / fmaxf(cnt[n], 1.0f);
    }
}

extern "C" void kernel_launch(void* const* d_in, const int* in_sizes, int n_in,
                              void* d_out, int out_size, void* d_ws, size_t ws_size,
                              hipStream_t stream)
{
    const float* node_attr  = (const float*)d_in[0];
    const float* edge_attr  = (const float*)d_in[1];
    const float* edge_sh    = (const float*)d_in[2];
    const float* fc1_w      = (const float*)d_in[3];
    const float* fc1_b      = (const float*)d_in[4];
    const float* fc2_w      = (const float*)d_in[5];
    const float* fc2_b      = (const float*)d_in[6];
    const int*   edge_index = (const int*)d_in[7];

    const int N = in_sizes[0] / NS;
    const int E = in_sizes[1] / NS;
    const int nb = (N + 255) / 256;          // scan blocks

    char* ws = (char*)d_ws;
    size_t off = 0;
    auto take = [&](size_t bytes) { off = (off + 255) & ~(size_t)255;
                                    size_t o = off; off += bytes; return o; };
    const size_t o_pk1    = take(PK1_ELEMS * 2);
    const size_t o_pk2    = take(PK2_ELEMS * 2);
    const size_t o_count  = take((size_t)N * 4);
    const size_t o_cursor = take((size_t)N * 4);
    const size_t o_base   = take((size_t)N * 4);
    const size_t o_bsum   = take(1024);
    const size_t o_boff   = take(1024);
    const size_t o_tot    = take(256);
    const size_t o_elist  = take((size_t)E * 4);
    const size_t o_msg    = take((size_t)E * MSGP * 4);
    const bool csr_ok = (off <= ws_size) && (nb <= 256);

    __bf16* pk1 = (__bf16*)(ws + o_pk1);
    __bf16* pk2 = (__bf16*)(ws + o_pk2);
    pack_weights<<<40, 256, 0, stream>>>(fc1_w, fc2_w, pk1, pk2);

    float* out = (float*)d_out;
    const int egrid = (E + 127) / 128;

    if (csr_ok) {
        int* count  = (int*)(ws + o_count);
        int* cursor = (int*)(ws + o_cursor);
        int* base   = (int*)(ws + o_base);
        int* bsum   = (int*)(ws + o_bsum);
        int* boff   = (int*)(ws + o_boff);
        int* tot    = (int*)(ws + o_tot);
        int* elist  = (int*)(ws + o_elist);
        float* msg  = (float*)(ws + o_msg);

        hipMemsetAsync(count,  0, (size_t)N * 4, stream);
        hipMemsetAsync(cursor, 0, (size_t)N * 4, stream);

        histo_kernel<<<(E + 255) / 256, 256, 0, stream>>>(edge_index, count, E);
        scan_block<<<nb, 256, 0, stream>>>(count, base, bsum, N);
        scan_block<<<1, 256, 0, stream>>>(bsum, boff, tot, nb);
        fill_csr<<<(E + 255) / 256, 256, 0, stream>>>(edge_index, base, boff,
                                                      cursor, elist, E);

        edge_mfma_kernel<0><<<egrid, 256, 0, stream>>>(node_attr, edge_attr, edge_sh,
                                                       fc1_b, fc2_b, edge_index,
                                                       pk1, pk2, msg, nullptr, E);

        node_reduce<<<(N + 7) / 8, 256, 0, stream>>>(msg, elist, count, base, boff,
                                                     out, N);
    } else {
        float* cntp = (float*)(ws + o_count);
        hipMemsetAsync(d_out, 0, (size_t)out_size * sizeof(float), stream);
        hipMemsetAsync(cntp, 0, (size_t)N * 4, stream);
        edge_mfma_kernel<1><<<egrid, 256, 0, stream>>>(node_attr, edge_attr, edge_sh,
                                                       fc1_b, fc2_b, edge_index,
                                                       pk1, pk2, out, cntp, E);
        const int total = N * MSG;
        finalize_kernel<<<(total + 255) / 256, 256, 0, stream>>>(out, cntp, total);
    }
}